// Round 12
// baseline (86.331 us; speedup 1.0000x reference)
//
#include <hip/hip_runtime.h>
#include <stdint.h>

#define IN_C 256
#define OUT_C 256
#define HH 56
#define WW 56
#define NB 32
#define HP 58
#define WP 58

#define NTILE 1792          // 32 img * 28 row-pairs * 2 oc-halves
#define ROW_B 3712          // 58 cols * 64 B
#define QPLANE_B 215296     // 58 rows * ROW_B
#define IMG_B 861184        // 4 q * QPLANE_B
#define SLAB_B 14848        // 4 rows * ROW_B
#define SLAB_CH 928         // 16B chunks per slab

typedef __attribute__((ext_vector_type(4))) int int4v;
typedef __attribute__((ext_vector_type(4))) float float4_t;

typedef const __attribute__((address_space(1))) unsigned int guint_t;
typedef __attribute__((address_space(3))) unsigned int luint_t;

__device__ __forceinline__ void gload16(void* lds, const void* g) {
    __builtin_amdgcn_global_load_lds((guint_t*)g, (luint_t*)lds, 16, 0, 0);
}

// quantize: x -> round(clamp(x*127/5)) as byte
__device__ __forceinline__ int q8(float f) {
    float c = fminf(fmaxf(f * 25.4f, -127.f), 127.f);
    return __float2int_rn(c) & 255;
}

// ---- fused pre-pass: blocks [0,1856) pad+quantize X; blocks [1856,2000) convert W ----
// X: NCHW f32 -> xq[n][q][row][col][64] i8, swizzle baked in:
//    physical 16B chunk pc of cell (row,col,q) holds ic range (pc ^ g(col))*16,
//    g(col) = (col&3) ^ ((col>>2)&3)
// W: OIHW f32 -> A-frag-ready i8, chunk i = [qt][s8][af][lane]
__global__ __launch_bounds__(256) void prep(const float* __restrict__ x,
                                            unsigned char* __restrict__ xq,
                                            const float* __restrict__ w,
                                            unsigned char* __restrict__ wfr) {
    int bid = blockIdx.x;
    if (bid >= NB * HP) {
        // ---------------- weight conversion ----------------
        int i = (bid - NB * HP) * 256 + threadIdx.x;     // 36864 chunks
        int lane = i & 63;
        int af = (i >> 6) & 1;
        int s8 = (i >> 7) & 7;
        int qt = i >> 10;                                // 0..35
        int tap = qt % 9, q = qt / 9;
        int oc = s8 * 32 + af * 16 + (lane & 15);
        int ic0 = q * 64 + (lane >> 4) * 16;
        int4v v;
#pragma unroll
        for (int wi = 0; wi < 4; ++wi) {
            int word = 0;
#pragma unroll
            for (int j = 0; j < 4; ++j)
                word |= (__float2int_rn(
                             w[(size_t)oc * 2304 + (size_t)(ic0 + wi * 4 + j) * 9 + tap]) &
                         255)
                        << (8 * j);
            v[wi] = word;
        }
        *(int4v*)(wfr + (size_t)i * 16) = v;
        return;
    }

    // ---------------- X pad + quantize ----------------
    __shared__ float lds[WW * 257];
    int n = bid / HP, h = bid % HP;
    bool hin = (h >= 1 && h <= HH);
    if (hin) {
        const float* src = x + (size_t)n * IN_C * (HH * WW) + (h - 1) * WW;
        // vectorized float4 gather: 3584 float4s, 14 per thread
        for (int e = threadIdx.x; e < IN_C * (WW / 4); e += 256) {
            int ic = e / (WW / 4), wq = e - ic * (WW / 4);
            float4_t v = *(const float4_t*)(src + (size_t)ic * (HH * WW) + wq * 4);
#pragma unroll
            for (int j = 0; j < 4; ++j) lds[(wq * 4 + j) * 257 + ic] = v[j];
        }
    }
    __syncthreads();
    unsigned char* dstn = xq + (size_t)n * IMG_B + (size_t)h * ROW_B;
    for (int e = threadIdx.x; e < 928; e += 256) {       // 4q * 58col * 4pc
        int q = e / 232, rem = e - q * 232;
        int col = rem >> 2, pc = rem & 3;
        int4v v = {0, 0, 0, 0};
        if (hin && col >= 1 && col <= WW) {
            int g = (col & 3) ^ ((col >> 2) & 3);
            int ic0 = q * 64 + ((pc ^ g) & 3) * 16;
            const float* p = &lds[(col - 1) * 257 + ic0];
#pragma unroll
            for (int wi = 0; wi < 4; ++wi) {
                int word = 0;
#pragma unroll
                for (int j = 0; j < 4; ++j) word |= q8(p[wi * 4 + j]) << (8 * j);
                v[wi] = word;
            }
        }
        *(int4v*)(dstn + (size_t)q * QPLANE_B + col * 64 + pc * 16) = v;
    }
}

// ---- main: i8 implicit-GEMM, 4-wave blocks (32oc x 112px), 3 blocks/CU, slab dbuf ----
__global__ __launch_bounds__(256, 3) void conv_i8(const unsigned char* __restrict__ xq,
                                                  const unsigned char* __restrict__ wfr,
                                                  float* __restrict__ out) {
    __shared__ unsigned char Xl[2][SLAB_B];

    const int tid = threadIdx.x;
    const int lane = tid & 63;
    const int wid = tid >> 6;

    const int bid = blockIdx.x;
    const int xcd = bid & 7, loc = bid >> 3;     // 4 images per XCD
    const int n = xcd * 4 + loc / 56;
    const int r = loc % 56;
    const int h = r & 1;                         // oc half
    const int rg = r >> 1;
    const int oh0 = rg * 2;
    const int pix0 = rg * 112;

    const unsigned char* xslab = xq + (size_t)n * IMG_B + (size_t)oh0 * ROW_B;

    const int rlo = lane & 15;
    const int kq = lane >> 4;
    int off[7][3];                               // cell byte offset incl. read swizzle
#pragma unroll
    for (int xf = 0; xf < 7; ++xf) {
        int pl = xf * 16 + rlo;
        int ohr = (pl >= 56) ? 1 : 0;
        int ow = pl - 56 * ohr;
#pragma unroll
        for (int kw = 0; kw < 3; ++kw) {
            int c = ow + kw;
            int g = (c & 3) ^ ((c >> 2) & 3);
            off[xf][kw] = (ohr * 58 + c) * 64 + ((kq ^ g) & 3) * 16;
        }
    }

    const int4v* wv = (const int4v*)wfr;
    const int abase = (h * 4 + wid) * 128 + lane;   // + qt*1024 (+af*64)

    int4v acc[2][7];
#pragma unroll
    for (int af = 0; af < 2; ++af)
#pragma unroll
        for (int xf = 0; xf < 7; ++xf) acc[af][xf] = {0, 0, 0, 0};

    int4v A0[2], A1[2], B[7];

#define LOAD_A(AF, QT)                                                         \
    {                                                                           \
        const int4v* p_ = wv + (QT) * 1024 + abase;                             \
        AF[0] = p_[0];                                                          \
        AF[1] = p_[64];                                                         \
    }

#define READ_B(TAP, SL)                                                        \
    {                                                                           \
        _Pragma("unroll")                                                       \
        for (int xf_ = 0; xf_ < 7; ++xf_)                                       \
            B[xf_] = *(const int4v*)(&(SL)[((TAP) / 3) * ROW_B + off[xf_][(TAP) % 3]]); \
    }

#define MMA(AF)                                                                \
    {                                                                           \
        __builtin_amdgcn_s_setprio(1);                                          \
        _Pragma("unroll")                                                       \
        for (int xf_ = 0; xf_ < 7; ++xf_)                                       \
            _Pragma("unroll")                                                   \
            for (int af_ = 0; af_ < 2; ++af_)                                   \
                acc[af_][xf_] = __builtin_amdgcn_mfma_i32_16x16x64_i8(          \
                    AF[af_], B[xf_], acc[af_][xf_], 0, 0, 0);                   \
        __builtin_amdgcn_s_setprio(0);                                          \
    }

    // ---- prologue: A(t=0) + slab q=0 (linear copy, swizzle pre-baked) ----
    LOAD_A(A0, 0);
#pragma unroll
    for (int k = 0; k < 3; ++k)
        gload16(&Xl[0][(tid + k * 256) * 16], xslab + (size_t)(tid + k * 256) * 16);
    if (tid < SLAB_CH - 768)
        gload16(&Xl[0][(tid + 768) * 16], xslab + (size_t)(tid + 768) * 16);
    asm volatile("s_waitcnt vmcnt(0)" ::: "memory");
    __builtin_amdgcn_s_barrier();
    __builtin_amdgcn_sched_barrier(0);

#pragma unroll
    for (int q = 0; q < 4; ++q) {
        const unsigned char* SL = Xl[q & 1];
        unsigned char* NS = Xl[(q & 1) ^ 1];
        const unsigned char* nsrc = xslab + (size_t)(q + 1) * QPLANE_B;
#pragma unroll
        for (int s = 0; s < 9; ++s) {
            const int t = q * 9 + s;
            if (t < 35) {
                if (t & 1) { LOAD_A(A0, t + 1); } else { LOAD_A(A1, t + 1); }
            }
            // drip-prefetch next q's slab at steps 2..5 (>=3 steps of cover)
            if (q < 3 && s >= 2 && s <= 5) {
                const int k = s - 2;
                if (k < 3)
                    gload16(&NS[(tid + k * 256) * 16], nsrc + (size_t)(tid + k * 256) * 16);
                else if (tid < SLAB_CH - 768)
                    gload16(&NS[(tid + 768) * 16], nsrc + (size_t)(tid + 768) * 16);
            }
            READ_B(s, SL);
            __builtin_amdgcn_sched_barrier(0);
            if (t & 1) { MMA(A1); } else { MMA(A0); }
        }
        if (q < 3) {
            asm volatile("s_waitcnt vmcnt(0)" ::: "memory");   // prefetches long done
            __builtin_amdgcn_s_barrier();
        }
    }

    // ---- epilogue: col = lane&15 -> pixel, row = kq*4+reg -> oc; dequant ----
    const float S = 5.0f / 127.0f;
    float* outn = out + (size_t)n * (OUT_C * HH * WW) + pix0 + rlo;
    const int ocb = h * 128 + wid * 32 + kq * 4;
#pragma unroll
    for (int af = 0; af < 2; ++af)
#pragma unroll
        for (int rr = 0; rr < 4; ++rr) {
            float* op = outn + (size_t)(ocb + af * 16 + rr) * (HH * WW);
#pragma unroll
            for (int xf = 0; xf < 7; ++xf)
                op[xf * 16] = (float)acc[af][xf][rr] * S;
        }
}

extern "C" void kernel_launch(void* const* d_in, const int* in_sizes, int n_in,
                              void* d_out, int out_size, void* d_ws, size_t ws_size,
                              hipStream_t stream) {
    const float* x = (const float*)d_in[0];
    const float* wgt = (const float*)d_in[1];
    float* out = (float*)d_out;

    unsigned char* xqb = (unsigned char*)d_ws;                     // 27.6 MB
    unsigned char* wfr = xqb + (size_t)NB * IMG_B;                 // 0.59 MB

    hipLaunchKernelGGL(prep, dim3(NB * HP + 144), dim3(256), 0, stream, x, xqb, wgt, wfr);
    hipLaunchKernelGGL(conv_i8, dim3(NTILE), dim3(256), 0, stream, xqb, wfr, out);
}